// Round 7
// baseline (212.990 us; speedup 1.0000x reference)
//
#include <hip/hip_runtime.h>
#include <math.h>

#define CIN   3
#define COUT  16
#define DHW   64
#define WPAD  28                      // 27 weights padded to 28 -> every group 16B-aligned

typedef float v2f __attribute__((ext_vector_type(2)));

static __device__ __forceinline__ v2f splat2(float s) { v2f r; r.x = s; r.y = s; return r; }

// Prep: pad-copy weights [48][27] -> [48][28] in workspace so each (c,co)
// group is 16B-aligned for global_load_dwordx4.
__global__ void pad_weights(const float* __restrict__ w, float* __restrict__ wpad) {
    const int i = threadIdx.x + blockIdx.x * 256;
    if (i < CIN * COUT * 27) {
        const int g = i / 27, r = i - g * 27;
        wpad[g * WPAD + r] = w[i];
    }
}

// One thread per FOUR output voxels (n,d,h,w0..w0+3), two packed fp32 pairs
// (v_pk_fma_f32). Weights delivered via VMEM (global_load_dwordx4, L1-hot,
// wave-uniform address = single broadcast transaction, 64-deep vmcnt queue).
// R2-6 post-mortem: SMEM (s_load) and LDS (ds_read) weight paths both plateau
// ~46-51us -- shallow/shared queues serialize the 48 weight-group fetches and
// neither VALU (55%) nor LDS pipe saturates. The asm "+v" launder below stops
// the compiler from folding the uniform address back into s_load.
//
// ConvTranspose3d(k=3,s=2,p=1,op=1) + MaxPool3d(2,2) fused:
//   od = 2*id - 1 + kd  =>  kd==1 -> even pool pos, id=d ; kd==0 -> odd, id=d+1 ;
//   kd==2 -> odd, id=d.  Each of 27 taps hits exactly one of 8 pool positions.
__global__ __launch_bounds__(128, 4) void fused_convt_pool_softmax_swish_max(
    const float* __restrict__ x,      // [N,CIN,64,64,64]
    const float* __restrict__ wpad,   // [48][WPAD] padded weights (d_ws)
    const float* __restrict__ bias,   // [COUT]
    const float* __restrict__ sub,    // [COUT]
    float* __restrict__ out)          // [N,64,64,64]
{
    const int tx = threadIdx.x;                      // w-quad index, 0..15
    const int h  = blockIdx.x * blockDim.y + threadIdx.y;
    const int d  = blockIdx.y;
    const int n  = blockIdx.z;
    const int w0 = tx * 4;                           // outputs w0..w0+3; inputs w0..w0+4

    // Launder weight pointer into VGPRs: forces global_load (VMEM) instead of
    // s_load (SMEM) despite the wave-uniform address.
    uintptr_t wbits = (uintptr_t)wpad;
    asm volatile("" : "+v"(wbits));
    const float* wv = (const float*)wbits;

    // P[c][dd][hh][j] = { x[w0+j], x[w0+j+1] }, j = 0..3
    v2f P[CIN][2][2][4];
    const size_t nbase = (size_t)n * CIN * DHW * DHW * DHW;
    const bool w4ok = (w0 + 4 < DHW);
    const int  off4 = w4ok ? 4 : 0;                  // clamped offset, stays in-bounds
#pragma unroll
    for (int c = 0; c < CIN; ++c) {
#pragma unroll
        for (int dd = 0; dd < 2; ++dd) {
#pragma unroll
            for (int hh = 0; hh < 2; ++hh) {
                const int id = d + dd;
                const int ih = h + hh;
                float4 q = make_float4(0.f, 0.f, 0.f, 0.f);
                float x4 = 0.0f;
                if (id < DHW && ih < DHW) {
                    const float* row = x + nbase + (((size_t)c * DHW + id) * DHW + ih) * DHW + w0;
                    q = *(const float4*)row;                  // 16B-aligned (w0 = 4*tx)
                    const float t = row[off4];
                    x4 = w4ok ? t : 0.0f;
                }
                v2f p0; p0.x = q.x; p0.y = q.y;
                v2f p1; p1.x = q.y; p1.y = q.z;
                v2f p2; p2.x = q.z; p2.y = q.w;
                v2f p3; p3.x = q.w; p3.y = x4;
                P[c][dd][hh][0] = p0;
                P[c][dd][hh][1] = p1;
                P[c][dd][hh][2] = p2;
                P[c][dd][hh][3] = p3;
            }
        }
    }

    v2f pooled[2][COUT];                             // [w-pair p][co]
#pragma unroll
    for (int co = 0; co < COUT; ++co) {
        v2f acc[2][2][2][2];                         // [p][pd][ph][pw]
#pragma unroll
        for (int i = 0; i < 16; ++i) (&acc[0][0][0][0])[i] = splat2(0.0f);
#pragma unroll
        for (int c = 0; c < CIN; ++c) {
            // 28-float group, 16B-aligned -> 7x global_load_dwordx4 (L1-hot broadcast)
            const float4* wq = (const float4*)(wv + (c * COUT + co) * WPAD);
            float4 qw[7];
#pragma unroll
            for (int t = 0; t < 7; ++t) qw[t] = wq[t];
            const float* wf = (const float*)&qw[0];  // wf[0..26], compile-time idx
#pragma unroll
            for (int kd = 0; kd < 3; ++kd) {
                const int pd = (kd == 1) ? 0 : 1;
                const int dd = (kd == 0) ? 1 : 0;
#pragma unroll
                for (int kh = 0; kh < 3; ++kh) {
                    const int ph = (kh == 1) ? 0 : 1;
                    const int hh = (kh == 0) ? 1 : 0;
#pragma unroll
                    for (int kw = 0; kw < 3; ++kw) {
                        const int pw = (kw == 1) ? 0 : 1;
                        const int ww = (kw == 0) ? 1 : 0;
                        const float wt = wf[kd * 9 + kh * 3 + kw];
#pragma unroll
                        for (int p = 0; p < 2; ++p)  // voxels (w0+2p, w0+2p+1)
                            acc[p][pd][ph][pw] = __builtin_elementwise_fma(
                                splat2(wt), P[c][dd][hh][2 * p + ww], acc[p][pd][ph][pw]);
                    }
                }
            }
        }
        const float bco = bias[co];
#pragma unroll
        for (int p = 0; p < 2; ++p) {
            const v2f* a = &acc[p][0][0][0];
            v2f m0 = __builtin_elementwise_max(__builtin_elementwise_max(a[0], a[1]), a[2]);
            v2f m1 = __builtin_elementwise_max(__builtin_elementwise_max(a[3], a[4]), a[5]);
            v2f m2 = __builtin_elementwise_max(__builtin_elementwise_max(a[6], a[7]), m0);
            pooled[p][co] = __builtin_elementwise_max(m1, m2) + splat2(bco);
        }
    }

    // channel softmax + subtract + swish + channel max, packed per w-pair.
    // swish monotone for z > -1.2785; z = softmax - sub >= -max|sub| ~ -0.3,
    // so max_co swish(z_co) = swish(max_co z_co).
    float4 resq;
    float* resf = (float*)&resq;
#pragma unroll
    for (int p = 0; p < 2; ++p) {
        v2f m = pooled[p][0];
#pragma unroll
        for (int co = 1; co < COUT; ++co) m = __builtin_elementwise_max(m, pooled[p][co]);
        v2f e[COUT];
        v2f s = splat2(0.0f);
#pragma unroll
        for (int co = 0; co < COUT; ++co) {
            v2f t = pooled[p][co] - m;
            v2f ev; ev.x = __expf(t.x); ev.y = __expf(t.y);
            e[co] = ev;
            s += ev;
        }
        v2f inv; inv.x = __builtin_amdgcn_rcpf(s.x); inv.y = __builtin_amdgcn_rcpf(s.y);
        v2f zmax = splat2(-3.402823466e+38f);
#pragma unroll
        for (int co = 0; co < COUT; ++co)
            zmax = __builtin_elementwise_max(
                zmax, __builtin_elementwise_fma(e[co], inv, splat2(-sub[co])));
        resf[2 * p + 0] = zmax.x * __builtin_amdgcn_rcpf(1.0f + __expf(-zmax.x));
        resf[2 * p + 1] = zmax.y * __builtin_amdgcn_rcpf(1.0f + __expf(-zmax.y));
    }

    float* op = out + (((size_t)n * DHW + d) * DHW + h) * DHW + w0;
    *(float4*)op = resq;                             // coalesced 16B store
}

extern "C" void kernel_launch(void* const* d_in, const int* in_sizes, int n_in,
                              void* d_out, int out_size, void* d_ws, size_t ws_size,
                              hipStream_t stream) {
    const float* x   = (const float*)d_in[0];
    const float* w   = (const float*)d_in[1];
    const float* b   = (const float*)d_in[2];
    const float* sub = (const float*)d_in[3];
    float* out  = (float*)d_out;
    float* wpad = (float*)d_ws;                      // 48*28*4 = 5376 B of scratch

    pad_weights<<<dim3(6), dim3(256), 0, stream>>>(w, wpad);

    dim3 block(16, 8, 1);                 // 16 w-quads x 8 h-rows = 128 threads (2 waves)
    dim3 grid(DHW / 8, DHW, 4);           // (h-groups, d, n) = 2048 blocks
    fused_convt_pool_softmax_swish_max<<<grid, block, 0, stream>>>(x, wpad, b, sub, out);
}

// Round 8
// 108.458 us; speedup vs baseline: 1.9638x; 1.9638x over previous
//
#include <hip/hip_runtime.h>
#include <math.h>

#define CIN   3
#define COUT  16
#define DHW   64
#define WPAD  28                      // 27 weights padded to 28 -> every group 16B-aligned
#define BX    16                      // w-quads per block
#define BY    8                       // h rows per block (128 threads = 2 waves)

typedef float v2f __attribute__((ext_vector_type(2)));

static __device__ __forceinline__ v2f splat2(float s) { v2f r; r.x = s; r.y = s; return r; }

// One thread per FOUR output voxels (n,d,h,w0..w0+3), two packed fp32 pairs.
// R8 structural change: co is a DYNAMIC #pragma unroll 1 loop. R1-R6 bodies
// were ~25-35KB of straight-line code with zero reuse -> continuous L1
// I-cache miss streaming was the invariant behind the 46-51us plateau
// (dur insensitive to VALU halving, weight-path changes, voxels/thread).
// Loop body ~1.6KB executes 16x from cache. pooled[co] (dynamic index) parks
// in LDS [co][tid]; bias applied in the statically-unrolled epilogue.
// R7 lesson: no pointer laundering - spilled everything to scratch (265MB fetch).
//
// ConvTranspose3d(k=3,s=2,p=1,op=1) + MaxPool3d(2,2) fused:
//   od = 2*id - 1 + kd  =>  kd==1 -> even pool pos, id=d ; kd==0 -> odd, id=d+1 ;
//   kd==2 -> odd, id=d.  Each of 27 taps hits exactly one of 8 pool positions.
__global__ __launch_bounds__(128, 2) void fused_convt_pool_softmax_swish_max(
    const float* __restrict__ x,      // [N,CIN,64,64,64]
    const float* __restrict__ w,      // [CIN,COUT,3,3,3]
    const float* __restrict__ bias,   // [COUT]
    const float* __restrict__ sub,    // [COUT]
    float* __restrict__ out)          // [N,64,64,64]
{
    __shared__ float  wsm[CIN * COUT * WPAD];          // 5376 B
    __shared__ float4 plds[COUT][BX * BY];             // 16*128*16 = 32768 B

    const int tid = threadIdx.y * BX + threadIdx.x;
    for (int i = tid; i < CIN * COUT * 27; i += BX * BY) {   // coalesced staging
        const int g = i / 27, r = i - g * 27;
        wsm[g * WPAD + r] = w[i];
    }
    __syncthreads();

    const int tx = threadIdx.x;                      // w-quad index, 0..15
    const int h  = blockIdx.x * BY + threadIdx.y;
    const int d  = blockIdx.y;
    const int n  = blockIdx.z;
    const int w0 = tx * 4;                           // outputs w0..w0+3; inputs w0..w0+4

    // P[c][dd][hh][j] = { x[w0+j], x[w0+j+1] }, j = 0..3  (loop-invariant)
    v2f P[CIN][2][2][4];
    const size_t nbase = (size_t)n * CIN * DHW * DHW * DHW;
    const bool w4ok = (w0 + 4 < DHW);
    const int  off4 = w4ok ? 4 : 0;                  // clamped offset, stays in-bounds
#pragma unroll
    for (int c = 0; c < CIN; ++c) {
#pragma unroll
        for (int dd = 0; dd < 2; ++dd) {
#pragma unroll
            for (int hh = 0; hh < 2; ++hh) {
                const int id = d + dd;
                const int ih = h + hh;
                float4 q = make_float4(0.f, 0.f, 0.f, 0.f);
                float x4 = 0.0f;
                if (id < DHW && ih < DHW) {
                    const float* row = x + nbase + (((size_t)c * DHW + id) * DHW + ih) * DHW + w0;
                    q = *(const float4*)row;                  // 16B-aligned (w0 = 4*tx)
                    const float t = row[off4];
                    x4 = w4ok ? t : 0.0f;
                }
                v2f p0; p0.x = q.x; p0.y = q.y;
                v2f p1; p1.x = q.y; p1.y = q.z;
                v2f p2; p2.x = q.z; p2.y = q.w;
                v2f p3; p3.x = q.w; p3.y = x4;
                P[c][dd][hh][0] = p0;
                P[c][dd][hh][1] = p1;
                P[c][dd][hh][2] = p2;
                P[c][dd][hh][3] = p3;
            }
        }
    }

    // ---- dynamic co loop: ~1.6KB body, executes 16x from I-cache ----
#pragma unroll 1
    for (int co = 0; co < COUT; ++co) {
        v2f acc[2][2][2][2];                         // [p][pd][ph][pw]
#pragma unroll
        for (int i = 0; i < 16; ++i) (&acc[0][0][0][0])[i] = splat2(0.0f);
#pragma unroll
        for (int c = 0; c < CIN; ++c) {
            const float4* wq = (const float4*)&wsm[(c * COUT + co) * WPAD];
            float4 qw[7];
#pragma unroll
            for (int t = 0; t < 7; ++t) qw[t] = wq[t];       // 7x ds_read_b128 broadcast
            const float* wf = (const float*)&qw[0];          // wf[0..26], compile-time idx
#pragma unroll
            for (int kd = 0; kd < 3; ++kd) {
                const int pd = (kd == 1) ? 0 : 1;
                const int dd = (kd == 0) ? 1 : 0;
#pragma unroll
                for (int kh = 0; kh < 3; ++kh) {
                    const int ph = (kh == 1) ? 0 : 1;
                    const int hh = (kh == 0) ? 1 : 0;
#pragma unroll
                    for (int kw = 0; kw < 3; ++kw) {
                        const int pw = (kw == 1) ? 0 : 1;
                        const int ww = (kw == 0) ? 1 : 0;
                        const float wt = wf[kd * 9 + kh * 3 + kw];
#pragma unroll
                        for (int p = 0; p < 2; ++p)  // voxels (w0+2p, w0+2p+1)
                            acc[p][pd][ph][pw] = __builtin_elementwise_fma(
                                splat2(wt), P[c][dd][hh][2 * p + ww], acc[p][pd][ph][pw]);
                    }
                }
            }
        }
        float4 pr;
#pragma unroll
        for (int p = 0; p < 2; ++p) {
            const v2f* a = &acc[p][0][0][0];
            v2f m0 = __builtin_elementwise_max(__builtin_elementwise_max(a[0], a[1]), a[2]);
            v2f m1 = __builtin_elementwise_max(__builtin_elementwise_max(a[3], a[4]), a[5]);
            v2f m2 = __builtin_elementwise_max(__builtin_elementwise_max(a[6], a[7]), m0);
            v2f r  = __builtin_elementwise_max(m1, m2);      // pre-bias pooled pair
            if (p == 0) { pr.x = r.x; pr.y = r.y; }
            else        { pr.z = r.x; pr.w = r.y; }
        }
        plds[co][tid] = pr;                                  // ds_write_b128
    }

    // ---- epilogue (static): bias + softmax + subtract + swish + channel max ----
    // Same-thread LDS RAW is ordered by lgkmcnt waits; no barrier needed.
    v2f pooled[2][COUT];
#pragma unroll
    for (int co = 0; co < COUT; ++co) {
        const float4 q = plds[co][tid];
        const float bco = bias[co];                          // compile-time idx -> s_load
        v2f a; a.x = q.x + bco; a.y = q.y + bco;
        v2f b2; b2.x = q.z + bco; b2.y = q.w + bco;
        pooled[0][co] = a;
        pooled[1][co] = b2;
    }

    // swish monotone for z > -1.2785; z = softmax - sub >= -max|sub| ~ -0.3,
    // so max_co swish(z_co) = swish(max_co z_co).
    float4 resq;
    float* resf = (float*)&resq;
#pragma unroll
    for (int p = 0; p < 2; ++p) {
        v2f m = pooled[p][0];
#pragma unroll
        for (int co = 1; co < COUT; ++co) m = __builtin_elementwise_max(m, pooled[p][co]);
        v2f e[COUT];
        v2f s = splat2(0.0f);
#pragma unroll
        for (int co = 0; co < COUT; ++co) {
            v2f t = pooled[p][co] - m;
            v2f ev; ev.x = __expf(t.x); ev.y = __expf(t.y);
            e[co] = ev;
            s += ev;
        }
        v2f inv; inv.x = __builtin_amdgcn_rcpf(s.x); inv.y = __builtin_amdgcn_rcpf(s.y);
        v2f zmax = splat2(-3.402823466e+38f);
#pragma unroll
        for (int co = 0; co < COUT; ++co)
            zmax = __builtin_elementwise_max(
                zmax, __builtin_elementwise_fma(e[co], inv, splat2(-sub[co])));
        resf[2 * p + 0] = zmax.x * __builtin_amdgcn_rcpf(1.0f + __expf(-zmax.x));
        resf[2 * p + 1] = zmax.y * __builtin_amdgcn_rcpf(1.0f + __expf(-zmax.y));
    }

    float* op = out + (((size_t)n * DHW + d) * DHW + h) * DHW + w0;
    *(float4*)op = resq;                             // coalesced 16B store
}

extern "C" void kernel_launch(void* const* d_in, const int* in_sizes, int n_in,
                              void* d_out, int out_size, void* d_ws, size_t ws_size,
                              hipStream_t stream) {
    const float* x   = (const float*)d_in[0];
    const float* w   = (const float*)d_in[1];
    const float* b   = (const float*)d_in[2];
    const float* sub = (const float*)d_in[3];
    float* out = (float*)d_out;

    dim3 block(BX, BY, 1);                // 16 w-quads x 8 h-rows = 128 threads
    dim3 grid(DHW / BY, DHW, 4);          // (h-groups, d, n) = 2048 blocks
    fused_convt_pool_softmax_swish_max<<<grid, block, 0, stream>>>(x, w, b, sub, out);
}

// Round 9
// 105.351 us; speedup vs baseline: 2.0217x; 1.0295x over previous
//
#include <hip/hip_runtime.h>
#include <math.h>

#define CIN   3
#define COUT  16
#define DHW   64
#define WPAD  28                      // 27 weights padded to 28 floats -> 16B-aligned groups

typedef float v2f __attribute__((ext_vector_type(2)));

// Guaranteed packed FMA with FREE splat of the x operand:
//   lanes: lo: acc.x += w2.x * x2.x   (kd=1 tap, pd=0)
//          hi: acc.y += w2.y * x2.x   (kd=2 tap, pd=1)   [op_sel_hi[1]=0 -> src1 hi reads lo]
#define PK_FMA_XSPLAT(acc, w2, x2) \
    asm("v_pk_fma_f32 %0, %1, %2, %0 op_sel_hi:[1,0,1]" : "+v"(acc) : "v"(w2), "v"(x2))

// One thread per TWO output voxels (n,d,h,{2t,2t+1}).
// R9: d-axis repack. ConvT(k=3,s=2,p=1,op=1)+pool maps kd=1->pd=0(id=d),
// kd=2->pd=1(id=d), kd=0->pd=1(id=d+1). kd=1,2 share x(dd=0) -> one real
// v_pk_fma_f32 (weights pre-paired in LDS, x pairs {dd0,dd1} natural, splat
// via op_sel) + one scalar v_fma for kd=0 on x(dd=1) = 18 instr / 27 MACs,
// zero splat movs. R1-R8 evidence: the ~46-51us plateau tracked ~2.4x VALU
// instruction bloat (ext_vector "pk" never emitted real pk ops) that none of
// the weight-path/voxel-count/code-size changes touched.
__global__ __launch_bounds__(256, 3) void fused_convt_pool_softmax_swish_max(
    const float* __restrict__ x,      // [N,CIN,64,64,64]
    const float* __restrict__ w,      // [CIN,COUT,3,3,3]
    const float* __restrict__ bias,   // [COUT]
    const float* __restrict__ sub,    // [COUT]
    float* __restrict__ out)          // [N,64,64,64]
{
    // Per (c,co) group of 28 floats:
    //   slots 2j,2j+1 = { w[kd=1][j], w[kd=2][j] }  (j = kh*3+kw, 0..8)
    //   slots 18+j    =   w[kd=0][j]
    __shared__ float wsm[CIN * COUT * WPAD];         // 5376 B

    const int tid = threadIdx.y * 32 + threadIdx.x;
    for (int i = tid; i < CIN * COUT * 27; i += 256) {
        const int g  = i / 27, r = i - g * 27;
        const int kd = r / 9,  j = r - kd * 9;
        const int slot = (kd == 0) ? (18 + j) : (2 * j + (kd - 1));
        wsm[g * WPAD + slot] = w[i];
    }
    __syncthreads();

    const int tx = threadIdx.x;                      // w-pair index, 0..31
    const int h  = blockIdx.x * blockDim.y + threadIdx.y;
    const int d  = blockIdx.y;
    const int n  = blockIdx.z;
    const int w0 = tx * 2;                           // outputs w0, w0+1; inputs w0..w0+2

    // P[c][hh][jw] = { x[c][d+0][h+hh][w0+jw], x[c][d+1][h+hh][w0+jw] }, jw=0..2
    v2f P[CIN][2][3];
    const size_t nbase = (size_t)n * CIN * DHW * DHW * DHW;
    const bool w2ok = (w0 + 2 < DHW);
    const int  off2 = w2ok ? 2 : 0;                  // clamped, stays in-bounds
#pragma unroll
    for (int c = 0; c < CIN; ++c) {
#pragma unroll
        for (int hh = 0; hh < 2; ++hh) {
            float vd[2][3];                          // [dd][jw]
#pragma unroll
            for (int dd = 0; dd < 2; ++dd) {
                const int id = d + dd;
                const int ih = h + hh;
                float v0 = 0.f, v1 = 0.f, v2 = 0.f;
                if (id < DHW && ih < DHW) {
                    const float* row = x + nbase + (((size_t)c * DHW + id) * DHW + ih) * DHW + w0;
                    const float2 a = *(const float2*)row;    // 8B-aligned (w0 even)
                    v0 = a.x; v1 = a.y;
                    const float t = row[off2];
                    v2 = w2ok ? t : 0.0f;
                }
                vd[dd][0] = v0; vd[dd][1] = v1; vd[dd][2] = v2;
            }
#pragma unroll
            for (int jw = 0; jw < 3; ++jw) {
                v2f p; p.x = vd[0][jw]; p.y = vd[1][jw];
                P[c][hh][jw] = p;
            }
        }
    }

    float pooled[2][COUT];
#pragma unroll
    for (int co = 0; co < COUT; ++co) {
        v2f acc[2][2][2];                            // [voxel][ph][pw], v2f over pd
#pragma unroll
        for (int i = 0; i < 8; ++i) { v2f z; z.x = 0.f; z.y = 0.f; (&acc[0][0][0])[i] = z; }
#pragma unroll
        for (int c = 0; c < CIN; ++c) {
            const float4* wq4 = (const float4*)&wsm[(c * COUT + co) * WPAD];
            float4 qw[7];
#pragma unroll
            for (int t = 0; t < 7; ++t) qw[t] = wq4[t];      // 7x ds_read_b128 broadcast
            const v2f*   wp2 = (const v2f*)&qw[0];           // pairs j=0..8 at wp2[j]
            const float* wf  = (const float*)&qw[0];         // singles at wf[18+j]
#pragma unroll
            for (int kh = 0; kh < 3; ++kh) {
                const int ph = (kh == 1) ? 0 : 1;
                const int hh = (kh == 0) ? 1 : 0;
#pragma unroll
                for (int kw = 0; kw < 3; ++kw) {
                    const int pw = (kw == 1) ? 0 : 1;
                    const int ww = (kw == 0) ? 1 : 0;
                    const int j  = kh * 3 + kw;
                    const v2f   wpair = wp2[j];              // {w_kd1, w_kd2}
                    const float wsgl  = wf[18 + j];          // w_kd0
#pragma unroll
                    for (int v = 0; v < 2; ++v) {            // voxels w0+v
                        const v2f xp = P[c][hh][v + ww];     // {x_dd0, x_dd1}
                        PK_FMA_XSPLAT(acc[v][ph][pw], wpair, xp);           // kd=1,2
                        acc[v][ph][pw].y = fmaf(wsgl, xp.y, acc[v][ph][pw].y); // kd=0
                    }
                }
            }
        }
        const float bco = bias[co];
#pragma unroll
        for (int v = 0; v < 2; ++v) {
            v2f m01 = __builtin_elementwise_max(acc[v][0][0], acc[v][0][1]);
            v2f m23 = __builtin_elementwise_max(acc[v][1][0], acc[v][1][1]);
            v2f mm  = __builtin_elementwise_max(m01, m23);
            pooled[v][co] = fmaxf(mm.x, mm.y) + bco;
        }
    }

    // channel softmax + subtract + swish + channel max, per voxel.
    // swish monotone for z > -1.2785; z = softmax - sub >= -max|sub| ~ -0.3,
    // so max_co swish(z_co) = swish(max_co z_co).
    float res[2];
#pragma unroll
    for (int v = 0; v < 2; ++v) {
        float m = pooled[v][0];
#pragma unroll
        for (int co = 1; co < COUT; ++co) m = fmaxf(m, pooled[v][co]);
        float e[COUT];
        float s = 0.0f;
#pragma unroll
        for (int co = 0; co < COUT; ++co) {
            e[co] = __expf(pooled[v][co] - m);
            s += e[co];
        }
        const float inv = __builtin_amdgcn_rcpf(s);
        float zmax = -3.402823466e+38f;
#pragma unroll
        for (int co = 0; co < COUT; ++co)
            zmax = fmaxf(zmax, fmaf(e[co], inv, -sub[co]));
        res[v] = zmax * __builtin_amdgcn_rcpf(1.0f + __expf(-zmax));
    }

    float* op = out + (((size_t)n * DHW + d) * DHW + h) * DHW + w0;
    *(float2*)op = make_float2(res[0], res[1]);      // coalesced 8B store
}

extern "C" void kernel_launch(void* const* d_in, const int* in_sizes, int n_in,
                              void* d_out, int out_size, void* d_ws, size_t ws_size,
                              hipStream_t stream) {
    const float* x   = (const float*)d_in[0];
    const float* w   = (const float*)d_in[1];
    const float* b   = (const float*)d_in[2];
    const float* sub = (const float*)d_in[3];
    float* out = (float*)d_out;

    dim3 block(32, 8, 1);                 // 32 w-pairs x 8 h-rows = 256 threads
    dim3 grid(DHW / 8, DHW, 4);           // (h-groups, d, n) = 2048 blocks
    fused_convt_pool_softmax_swish_max<<<grid, block, 0, stream>>>(x, w, b, sub, out);
}